// Round 7
// baseline (66.736 us; speedup 1.0000x reference)
//
#include <hip/hip_runtime.h>

#define NH   8
#define LQ   32
#define NB   32              // n per block (256 thr = 32 n x 8 h)
#define X_LO 168             // x window rows [168,185]  (center 176)
#define NXW  18
#define Y_LO 192             // y window rows [192,209]  (center 200)
#define NYW  18
#define NZW  21              // z table staged fully; clip => always in window
#define NROWS (NXW + NYW + NZW)   // 57
#define ROWF 132             // floats per LDS row slot (528 B: 512 + 16 pad)

__global__ __launch_bounds__(256) void rpe_kernel(
    const float* __restrict__ relpos,
    const float* __restrict__ qfeat,
    const float* __restrict__ scaling,
    const float* __restrict__ tx,
    const float* __restrict__ ty,
    const float* __restrict__ tz,
    float* __restrict__ out, int N)
{
    __shared__ float lds[NROWS * ROWF];   // ~30.1 KB

    const int t = threadIdx.x;

    // ---- stage hot windows, transposed within row: piece (h,v) -> v*128B + h*16B
    // quad-bank of a row's piece = (row + h) mod 8  (528B stride => row*33 quads)
    for (int g = t; g < NROWS * 32; g += 256) {
        int r = g >> 5;              // staged row 0..56
        int p = g & 31;              // 16B piece within the 512B source row
        const float* src;
        if (r < NXW)              src = tx + (size_t)(X_LO + r) * 128 + p * 4;
        else if (r < NXW + NYW)   src = ty + (size_t)(Y_LO + (r - NXW)) * 128 + p * 4;
        else                      src = tz + (size_t)(r - NXW - NYW) * 128 + p * 4;
        float4 v = *(const float4*)src;
        int hh = p >> 2, vv = p & 3;
        *(float4*)&lds[r * ROWF + vv * 32 + hh * 4] = v;
    }
    __syncthreads();

    const int h  = t & 7;
    const int nl = t >> 3;           // 0..31
    const int gn = blockIdx.x * NB + nl;
    if (gn >= N) return;             // N=20000 divisible by 32; after barrier

    // qf[n,h,0:48] hoisted to registers (12 float4)
    const float4* q = (const float4*)(qfeat + (size_t)gn * (NH * 48) + h * 48);
    float4 qv[12];
#pragma unroll
    for (int v = 0; v < 12; ++v) qv[v] = q[v];

    const float s = scaling[0];
    const float* rp = relpos + (size_t)gn * (LQ * 3);
    float* outp = out + (size_t)gn * (LQ * NH) + h;

#pragma unroll 2
    for (int l = 0; l < LQ; ++l) {
        float rx = rp[l * 3 + 0];
        float ry = rp[l * 3 + 1];
        float rz = rp[l * 3 + 2];
        // XLA semantics: /0.4f canonicalized to *2.5f (exact), f32 add (R4-verified)
        int ix = min(max((int)floorf((rx + 70.4f) * 2.5f), 0), 352);
        int iy = min(max((int)floorf((ry + 80.0f) * 2.5f), 0), 400);
        int iz = min(max((int)floorf((rz + 4.0f)  * 2.5f), 0), 20);

        float4 ax0, ax1, ax2, ax3, ay0, ay1, ay2, ay3, az0, az1, az2, az3;

        unsigned ox = (unsigned)(ix - X_LO);
        if (ox < NXW) {
            const float* b = lds + ox * ROWF + h * 4;
            ax0 = *(const float4*)(b);      ax1 = *(const float4*)(b + 32);
            ax2 = *(const float4*)(b + 64); ax3 = *(const float4*)(b + 96);
        } else {   // rare fallback: exact global gather
            const float* gb = tx + (size_t)ix * 128 + h * 16;
            ax0 = *(const float4*)(gb);     ax1 = *(const float4*)(gb + 4);
            ax2 = *(const float4*)(gb + 8); ax3 = *(const float4*)(gb + 12);
        }

        unsigned oy = (unsigned)(iy - Y_LO);
        if (oy < NYW) {
            const float* b = lds + (NXW + oy) * ROWF + h * 4;
            ay0 = *(const float4*)(b);      ay1 = *(const float4*)(b + 32);
            ay2 = *(const float4*)(b + 64); ay3 = *(const float4*)(b + 96);
        } else {
            const float* gb = ty + (size_t)iy * 128 + h * 16;
            ay0 = *(const float4*)(gb);     ay1 = *(const float4*)(gb + 4);
            ay2 = *(const float4*)(gb + 8); ay3 = *(const float4*)(gb + 12);
        }

        {   // z always staged (clip guarantees 0..20)
            const float* b = lds + (NXW + NYW + iz) * ROWF + h * 4;
            az0 = *(const float4*)(b);      az1 = *(const float4*)(b + 32);
            az2 = *(const float4*)(b + 64); az3 = *(const float4*)(b + 96);
        }

        float acc = ax0.x*qv[0].x + ax0.y*qv[0].y + ax0.z*qv[0].z + ax0.w*qv[0].w
                  + ax1.x*qv[1].x + ax1.y*qv[1].y + ax1.z*qv[1].z + ax1.w*qv[1].w
                  + ax2.x*qv[2].x + ax2.y*qv[2].y + ax2.z*qv[2].z + ax2.w*qv[2].w
                  + ax3.x*qv[3].x + ax3.y*qv[3].y + ax3.z*qv[3].z + ax3.w*qv[3].w
                  + ay0.x*qv[4].x + ay0.y*qv[4].y + ay0.z*qv[4].z + ay0.w*qv[4].w
                  + ay1.x*qv[5].x + ay1.y*qv[5].y + ay1.z*qv[5].z + ay1.w*qv[5].w
                  + ay2.x*qv[6].x + ay2.y*qv[6].y + ay2.z*qv[6].z + ay2.w*qv[6].w
                  + ay3.x*qv[7].x + ay3.y*qv[7].y + ay3.z*qv[7].z + ay3.w*qv[7].w
                  + az0.x*qv[8].x + az0.y*qv[8].y + az0.z*qv[8].z + az0.w*qv[8].w
                  + az1.x*qv[9].x + az1.y*qv[9].y + az1.z*qv[9].z + az1.w*qv[9].w
                  + az2.x*qv[10].x + az2.y*qv[10].y + az2.z*qv[10].z + az2.w*qv[10].w
                  + az3.x*qv[11].x + az3.y*qv[11].y + az3.z*qv[11].z + az3.w*qv[11].w;

        outp[l * NH] = acc * s;
    }
}

extern "C" void kernel_launch(void* const* d_in, const int* in_sizes, int n_in,
                              void* d_out, int out_size, void* d_ws, size_t ws_size,
                              hipStream_t stream) {
    const float* relpos  = (const float*)d_in[0];
    const float* qfeat   = (const float*)d_in[1];
    const float* scaling = (const float*)d_in[2];
    // d_in[3] = query_batch_cnt (unused by reference math)
    const float* tx      = (const float*)d_in[4];
    const float* ty      = (const float*)d_in[5];
    const float* tz      = (const float*)d_in[6];
    float* out           = (float*)d_out;

    int N = in_sizes[0] / (LQ * 3);     // 20000
    int blocks = (N + NB - 1) / NB;     // 625

    rpe_kernel<<<blocks, 256, 0, stream>>>(relpos, qfeat, scaling, tx, ty, tz, out, N);
}

// Round 9
// 46.629 us; speedup vs baseline: 1.4312x; 1.4312x over previous
//
#include <hip/hip_runtime.h>

#define NH 8
#define LQ 32
#define NB 8   // n per block: one n per half-wave (256 thr = 8 half-waves)

typedef float f32x4 __attribute__((ext_vector_type(4)));

__global__ __launch_bounds__(256) void rpe_kernel(
    const float* __restrict__ relpos,
    const float* __restrict__ qfeat,
    const float* __restrict__ scaling,
    const float* __restrict__ tx,
    const float* __restrict__ ty,
    const float* __restrict__ tz,
    float* __restrict__ out, int N)
{
    int t  = threadIdx.x;
    int k  = t & 31;          // lane within half-wave: owns 16B piece k of a row
    int nl = t >> 5;          // 0..7
    int gn = blockIdx.x * NB + nl;
    if (gn >= N) return;

    int h  = k >> 2;          // head this lane's piece belongs to
    int d4 = k & 3;           // which float4 of the head's 16 dims

    // lane k computes the quantized indices for l = k (coalesced 12B/lane).
    // Streaming inputs are loaded non-temporal so the hot ~26KB table window
    // stays L1-resident (tables are the only temporal data).
    const float* rp = relpos + ((size_t)gn * LQ + k) * 3;
    float rx = __builtin_nontemporal_load(rp + 0);
    float ry = __builtin_nontemporal_load(rp + 1);
    float rz = __builtin_nontemporal_load(rp + 2);
    // XLA semantics: /0.4f canonicalized to *2.5f (exact), f32 add (R4-verified)
    int ix = min(max((int)floorf((rx + 70.4f) * 2.5f), 0), 352);
    int iy = min(max((int)floorf((ry + 80.0f) * 2.5f), 0), 400);
    int iz = min(max((int)floorf((rz + 4.0f)  * 2.5f), 0), 20);
    unsigned packed = (unsigned)ix | ((unsigned)iy << 9) | ((unsigned)iz << 18);

    // qf pieces for this lane (one float4 per axis), hoisted for the whole n
    const f32x4* qb = (const f32x4*)(qfeat + (size_t)gn * (NH * 48) + h * 48 + d4 * 4);
    f32x4 qx = __builtin_nontemporal_load(qb);
    f32x4 qy = __builtin_nontemporal_load(qb + 4);
    f32x4 qz = __builtin_nontemporal_load(qb + 8);

    const float s = scaling[0];
    const char* txb = (const char*)tx + k * 16;   // lane's 16B piece of any row
    const char* tyb = (const char*)ty + k * 16;
    const char* tzb = (const char*)tz + k * 16;
    float* outp = out + (size_t)gn * (LQ * NH);

#pragma unroll 4
    for (int l = 0; l < LQ; ++l) {
        unsigned p  = __shfl((int)packed, l, 32);
        unsigned jx = p & 511u;
        unsigned jy = (p >> 9) & 511u;
        unsigned jz = p >> 18;
        // contiguous 512B row reads across the half-wave; temporal -> L1-resident
        f32x4 ax = *(const f32x4*)(txb + ((size_t)jx << 9));
        f32x4 ay = *(const f32x4*)(tyb + ((size_t)jy << 9));
        f32x4 az = *(const f32x4*)(tzb + ((size_t)jz << 9));

        float acc = ax.x*qx.x + ax.y*qx.y + ax.z*qx.z + ax.w*qx.w
                  + ay.x*qy.x + ay.y*qy.y + ay.z*qy.z + ay.w*qy.w
                  + az.x*qz.x + az.y*qz.y + az.z*qz.z + az.w*qz.w;

        // reduce the 4-lane d-group -> full dot for head h
        acc += __shfl_xor(acc, 1, 32);
        acc += __shfl_xor(acc, 2, 32);

        if (d4 == 0)
            __builtin_nontemporal_store(acc * s, &outp[l * NH + h]);  // 8 consecutive floats
    }
}

extern "C" void kernel_launch(void* const* d_in, const int* in_sizes, int n_in,
                              void* d_out, int out_size, void* d_ws, size_t ws_size,
                              hipStream_t stream) {
    const float* relpos  = (const float*)d_in[0];
    const float* qfeat   = (const float*)d_in[1];
    const float* scaling = (const float*)d_in[2];
    // d_in[3] = query_batch_cnt (unused by reference math)
    const float* tx      = (const float*)d_in[4];
    const float* ty      = (const float*)d_in[5];
    const float* tz      = (const float*)d_in[6];
    float* out           = (float*)d_out;

    int N = in_sizes[0] / (LQ * 3);   // 20000
    int blocks = (N + NB - 1) / NB;   // 2500

    rpe_kernel<<<blocks, 256, 0, stream>>>(relpos, qfeat, scaling, tx, ty, tz, out, N);
}